// Round 8
// baseline (3792.423 us; speedup 1.0000x reference)
//
#include <hip/hip_runtime.h>

typedef unsigned short u16;
typedef float f32x4 __attribute__((ext_vector_type(4)));
typedef u16   u16x8 __attribute__((ext_vector_type(8)));

__device__ __forceinline__ u16 f2bf(float f) {
  __bf16 b = (__bf16)f;
  return __builtin_bit_cast(u16, b);
}
__device__ __forceinline__ float bf2f(u16 u) {
  unsigned int x = ((unsigned int)u) << 16;
  return __builtin_bit_cast(float, x);
}

// ---------------- tiled f32 GEMM --------------------------------------------
// C[m,n] = sum_k A[m,k]*W[n,k] + bias[n]   (nn.Linear: y = x@W.T + b)
// A: [M][1024] f32 (ABF16=0) or bf16 (ABF16=1). W: [1024][1024] f32 row-major.
// OUT_BF16=0: C float[M][1024]. OUT_BF16=1: C bf16[M][1024].
// 64x64 tile, BK=32, 256 threads, 4x4 micro-tile per thread.
template<int ABF16, int OUT_BF16>
__global__ __launch_bounds__(256) void gemm_f32(
    const void* __restrict__ Ap, const float* __restrict__ W,
    const float* __restrict__ bias, void* __restrict__ Cout, int M)
{
  __shared__ float Xs[64][33];
  __shared__ float Ws[64][33];
  const int tid = threadIdx.x;
  const int tx = tid & 15, ty = tid >> 4;
  const int row0 = blockIdx.x * 64, col0 = blockIdx.y * 64;
  float acc[4][4] = {};

  for (int k0 = 0; k0 < 1024; k0 += 32) {
    __syncthreads();
#pragma unroll
    for (int p = 0; p < 8; ++p) {
      int idx = p * 256 + tid;
      int r = idx >> 5, c = idx & 31;
      long ar = row0 + r; if (ar >= M) ar = M - 1;
      float xv;
      if constexpr (ABF16) xv = bf2f(((const u16*)Ap)[ar * 1024 + k0 + c]);
      else                 xv = ((const float*)Ap)[ar * 1024 + k0 + c];
      Xs[r][c] = xv;
      Ws[r][c] = W[(long)(col0 + r) * 1024 + k0 + c];
    }
    __syncthreads();
    for (int kk = 0; kk < 32; ++kk) {
      float xr[4], wr[4];
#pragma unroll
      for (int i = 0; i < 4; ++i) xr[i] = Xs[ty * 4 + i][kk];
#pragma unroll
      for (int j = 0; j < 4; ++j) wr[j] = Ws[tx * 4 + j][kk];
#pragma unroll
      for (int i = 0; i < 4; ++i)
#pragma unroll
        for (int j = 0; j < 4; ++j)
          acc[i][j] += xr[i] * wr[j];
    }
  }

#pragma unroll
  for (int i = 0; i < 4; ++i) {
    int m = row0 + ty * 4 + i;
    if (m >= M) continue;
#pragma unroll
    for (int j = 0; j < 4; ++j) {
      int n = col0 + tx * 4 + j;
      float r = acc[i][j] + bias[n];
      if constexpr (OUT_BF16) ((u16*)Cout)[(long)m * 1024 + n] = f2bf(r);
      else                    ((float*)Cout)[(long)m * 1024 + n] = r;
    }
  }
}

// ---------------- masked multi-head attention -------------------------------
// One wave per q-row. Lane owns keys ki = lane + 64*t; full 64-d dot per lane.
// Qf/Kf: [4000][1024] f32. Vb: [4000][1024] bf16.
// Aout: float[64][1000][1000] (f32 OUTPUT). ctx: bf16[4000][1024].
__global__ __launch_bounds__(256) void MaskedMultiheadAttention_51591147160164_kernel(
    const float* __restrict__ Qf, const float* __restrict__ Kf,
    const u16* __restrict__ Vb, const int* __restrict__ maskp,
    float* __restrict__ Aout, u16* __restrict__ ctx)
{
  const int tid = threadIdx.x;
  const int lane = tid & 63;
  const int qi = blockIdx.x * 4 + (tid >> 6);      // 0..999
  const int h = blockIdx.y, b = blockIdx.z;
  const long qrow = (long)(b * 1000 + qi) * 1024 + h * 64;

  // Q row into registers (all 64 d; identical across lanes)
  float qv[64];
#pragma unroll
  for (int u = 0; u < 16; ++u) {
    f32x4 t4 = *(const f32x4*)(Qf + qrow + u * 4);
#pragma unroll
    for (int e = 0; e < 4; ++e) qv[u * 4 + e] = t4[e];
  }

  // pass 1: scores + per-lane online max/sum
  float sv[16];
  float ml = -3.0e38f, ll = 0.f;
#pragma unroll
  for (int t = 0; t < 16; ++t) {
    const int ki = lane + 64 * t;
    if (ki > qi) break;                            // causal; monotone in t
    if (maskp[b * 1000 + ki] != 0) {
      const float* Krow = Kf + (long)(b * 1000 + ki) * 1024 + h * 64;
      float d = 0.f;
#pragma unroll
      for (int u = 0; u < 16; ++u) {
        f32x4 k4 = *(const f32x4*)(Krow + u * 4);
#pragma unroll
        for (int e = 0; e < 4; ++e) d += qv[u * 4 + e] * k4[e];
      }
      float s = d * 0.125f;                        // 1/sqrt(DK), DK=64
      sv[t] = s;
      if (s > ml) { ll = ll * __expf(ml - s) + 1.f; ml = s; }
      else        { ll += __expf(s - ml); }
    } else {
      sv[t] = -1.0e30f;                            // padding-masked -> p = 0
    }
  }

  // wave combine (64 lanes)
  float M = ml;
#pragma unroll
  for (int d = 1; d < 64; d <<= 1) M = fmaxf(M, __shfl_xor(M, d));
  float lw = (ml > -1.0e37f) ? ll * __expf(ml - M) : 0.f;
#pragma unroll
  for (int d = 1; d < 64; d <<= 1) lw += __shfl_xor(lw, d);
  const float rl = (lw > 0.f) ? 1.f / lw : 0.f;

  // pass 2: normalized probabilities -> A (f32), kept in regs for PV
  const long arow = ((long)(b * 16 + h) * 1000 + qi) * 1000;
#pragma unroll
  for (int t = 0; t < 16; ++t) {
    const int ki = lane + 64 * t;
    if (ki > qi) break;
    float p = __expf(sv[t] - M) * rl;
    sv[t] = p;
    Aout[arow + ki] = p;
  }

  // pass 3: ctx[qi][d=lane] = sum_ki p * V[ki][d] via shfl broadcast
  float acc = 0.f;
#pragma unroll
  for (int t = 0; t < 16; ++t) {
    if (64 * t > qi) break;                        // wave-uniform
    for (int kk = 0; kk < 64; ++kk) {
      const int ki = t * 64 + kk;
      if (ki > qi) break;                          // wave-uniform
      float p = __shfl(sv[t], kk);
      acc += p * bf2f(Vb[(long)(b * 1000 + ki) * 1024 + h * 64 + lane]);
    }
  }
  ctx[qrow + lane] = f2bf(acc);
}

// ---------------- launch ----------------------------------------------------
extern "C" void kernel_launch(void* const* d_in, const int* in_sizes, int n_in,
                              void* d_out, int out_size, void* d_ws, size_t ws_size,
                              hipStream_t stream)
{
  const float* q  = (const float*)d_in[0];
  const float* k  = (const float*)d_in[1];
  const float* v  = (const float*)d_in[2];
  const int*  msk = (const int*)d_in[3];
  const float* Wq = (const float*)d_in[4];
  const float* bq = (const float*)d_in[5];
  const float* Wk = (const float*)d_in[6];
  const float* bk = (const float*)d_in[7];
  const float* Wv = (const float*)d_in[8];
  const float* bv = (const float*)d_in[9];
  const float* Wp = (const float*)d_in[10];
  const float* bp = (const float*)d_in[11];

  // workspace: Qf, Kf f32 (A-accuracy needs f32 scores); Vb, ctx bf16. 49.15 MB.
  float* Qf = (float*)d_ws;                  // [4000][1024] f32
  float* Kf = Qf + 4096000;                  // [4000][1024] f32
  u16*  Vb  = (u16*)(Kf + 4096000);          // [4000][1024] bf16
  u16*  ctx = Vb + 4096000;                  // [4000][1024] bf16

  float* Xout = (float*)d_out;               // [4000][1024] f32 (output x)
  float* Aout = Xout + 4096000;              // [64][1000][1000] f32 (output A)

  gemm_f32<0, 0><<<dim3(63, 16), 256, 0, stream>>>(q, Wq, bq, Qf, 4000);
  gemm_f32<0, 0><<<dim3(63, 16), 256, 0, stream>>>(k, Wk, bk, Kf, 4000);
  gemm_f32<0, 1><<<dim3(63, 16), 256, 0, stream>>>(v, Wv, bv, Vb, 4000);
  MaskedMultiheadAttention_51591147160164_kernel<<<dim3(250, 16, 4), 256, 0, stream>>>(
      Qf, Kf, Vb, msk, Aout, ctx);
  gemm_f32<1, 0><<<dim3(63, 16), 256, 0, stream>>>(ctx, Wp, bp, Xout, 4000);
}

// Round 9
// 888.970 us; speedup vs baseline: 4.2661x; 4.2661x over previous
//
#include <hip/hip_runtime.h>

typedef unsigned short u16;
typedef __bf16 bf16x8 __attribute__((ext_vector_type(8)));
typedef float f32x4 __attribute__((ext_vector_type(4)));
typedef u16   u16x8 __attribute__((ext_vector_type(8)));

__device__ __forceinline__ u16 f2bf(float f) {
  __bf16 b = (__bf16)f;
  return __builtin_bit_cast(u16, b);
}
__device__ __forceinline__ float bf2f(u16 u) {
  unsigned int x = ((unsigned int)u) << 16;
  return __builtin_bit_cast(float, x);
}

// ---------------- tiled f32 GEMM (green baseline, unchanged) ----------------
// C[m,n] = sum_k A[m,k]*W[n,k] + bias[n]   (nn.Linear: y = x@W.T + b)
template<int ABF16, int OUT_BF16>
__global__ __launch_bounds__(256) void gemm_f32(
    const void* __restrict__ Ap, const float* __restrict__ W,
    const float* __restrict__ bias, void* __restrict__ Cout, int M)
{
  __shared__ float Xs[64][33];
  __shared__ float Ws[64][33];
  const int tid = threadIdx.x;
  const int tx = tid & 15, ty = tid >> 4;
  const int row0 = blockIdx.x * 64, col0 = blockIdx.y * 64;
  float acc[4][4] = {};

  for (int k0 = 0; k0 < 1024; k0 += 32) {
    __syncthreads();
#pragma unroll
    for (int p = 0; p < 8; ++p) {
      int idx = p * 256 + tid;
      int r = idx >> 5, c = idx & 31;
      long ar = row0 + r; if (ar >= M) ar = M - 1;
      float xv;
      if constexpr (ABF16) xv = bf2f(((const u16*)Ap)[ar * 1024 + k0 + c]);
      else                 xv = ((const float*)Ap)[ar * 1024 + k0 + c];
      Xs[r][c] = xv;
      Ws[r][c] = W[(long)(col0 + r) * 1024 + k0 + c];
    }
    __syncthreads();
    for (int kk = 0; kk < 32; ++kk) {
      float xr[4], wr[4];
#pragma unroll
      for (int i = 0; i < 4; ++i) xr[i] = Xs[ty * 4 + i][kk];
#pragma unroll
      for (int j = 0; j < 4; ++j) wr[j] = Ws[tx * 4 + j][kk];
#pragma unroll
      for (int i = 0; i < 4; ++i)
#pragma unroll
        for (int j = 0; j < 4; ++j)
          acc[i][j] += xr[i] * wr[j];
    }
  }

#pragma unroll
  for (int i = 0; i < 4; ++i) {
    int m = row0 + ty * 4 + i;
    if (m >= M) continue;
#pragma unroll
    for (int j = 0; j < 4; ++j) {
      int n = col0 + tx * 4 + j;
      float r = acc[i][j] + bias[n];
      if constexpr (OUT_BF16) ((u16*)Cout)[(long)m * 1024 + n] = f2bf(r);
      else                    ((float*)Cout)[(long)m * 1024 + n] = r;
    }
  }
}

// ---------------- MFMA flash attention --------------------------------------
// grid (16 qblocks reversed, 64 b*h), 256 thr = 4 waves; wave owns 16 q-rows.
// Qf/Kf: f32 [4000][1024] (converted bf16 at staging). Vb: bf16 [4000][1024].
// Two-pass online softmax. Aout: f32 [64][1000][1000]. ctx: bf16 [4000][1024].
// MFMA 16x16x32 bf16 conventions (HW-verified): A/B frag row=lane&15,
// k=8*(lane>>4)+e ; C/D col=lane&15, row=4*(lane>>4)+reg.
__global__ __launch_bounds__(256) void MaskedMultiheadAttention_51591147160164_kernel(
    const float* __restrict__ Qf, const float* __restrict__ Kf,
    const u16* __restrict__ Vb, const int* __restrict__ maskp,
    float* __restrict__ Aout, u16* __restrict__ ctx)
{
  __shared__ __align__(16) u16 Qs[64 * 72];
  __shared__ __align__(16) u16 Ks[32 * 72];
  __shared__ __align__(16) u16 Vs[64 * 40];      // V^T tile: [d=64][key=32]+pad
  __shared__ __align__(16) u16 Ps[4][16 * 40];   // per-wave P tile [16 q][32 k]+pad

  const int qb = 15 - blockIdx.x;                // heavy blocks dispatch first
  const int bh = blockIdx.y;
  const int b = bh >> 4, h = bh & 15;
  const int q0 = qb * 64;
  const int tid = threadIdx.x;
  const int wid = tid >> 6, lane = tid & 63, ln = lane & 15, lg = lane >> 4;
  const int nkt = 2 * qb + 2;                    // 32-wide k-tiles covering [0, q0+64)

  // ---- stage Q block (64 rows x 64 d), f32 -> bf16 ----
#pragma unroll
  for (int p = 0; p < 2; ++p) {
    int idx = p * 256 + tid;
    int r = idx >> 3, u = idx & 7;
    int tok = q0 + r; if (tok > 999) tok = 999;  // clamp (rows 1000..1023 unused)
    const float* src = Qf + (long)(b * 1000 + tok) * 1024 + h * 64 + u * 8;
    f32x4 a0 = *(const f32x4*)src;
    f32x4 a1 = *(const f32x4*)(src + 4);
    u16x8 w;
#pragma unroll
    for (int e = 0; e < 4; ++e) { w[e] = f2bf(a0[e]); w[e + 4] = f2bf(a1[e]); }
    *(u16x8*)&Qs[r * 72 + u * 8] = w;
  }
  __syncthreads();

  bf16x8 qf0, qf1;
  {
    int r = wid * 16 + ln;
    qf0 = *(const bf16x8*)&Qs[r * 72 +      8 * lg];
    qf1 = *(const bf16x8*)&Qs[r * 72 + 32 + 8 * lg];
  }

  const int kr = tid >> 3, ku = tid & 7;         // staging decomposition
  const int qrow = q0 + wid * 16 + 4 * lg;       // + reg = this lane's rows

  auto computeS = [&](f32x4 sf[2]) {
#pragma unroll
    for (int j = 0; j < 2; ++j) {
      int kk = j * 16 + ln;
      bf16x8 kf0 = *(const bf16x8*)&Ks[kk * 72 +      8 * lg];
      bf16x8 kf1 = *(const bf16x8*)&Ks[kk * 72 + 32 + 8 * lg];
      f32x4 z = {0.f, 0.f, 0.f, 0.f};
      z = __builtin_amdgcn_mfma_f32_16x16x32_bf16(qf0, kf0, z, 0, 0, 0);
      z = __builtin_amdgcn_mfma_f32_16x16x32_bf16(qf1, kf1, z, 0, 0, 0);
      sf[j] = z;
    }
  };

  float m[4], l[4];
#pragma unroll
  for (int i = 0; i < 4; ++i) { m[i] = -3.0e38f; l[i] = 0.f; }

  // ---- pass 1: row max + denom ----
  for (int kt = 0; kt < nkt; ++kt) {
    int tok = kt * 32 + kr; if (tok > 999) tok = 999;
    const float* ksrc = Kf + (long)(b * 1000 + tok) * 1024 + h * 64 + ku * 8;
    f32x4 a0 = *(const f32x4*)ksrc;
    f32x4 a1 = *(const f32x4*)(ksrc + 4);
    u16x8 w;
#pragma unroll
    for (int e = 0; e < 4; ++e) { w[e] = f2bf(a0[e]); w[e + 4] = f2bf(a1[e]); }
    __syncthreads();                              // previous tile reads done
    *(u16x8*)&Ks[kr * 72 + ku * 8] = w;
    __syncthreads();                              // tile staged

    f32x4 sf[2]; computeS(sf);
    int ki0 = kt * 32 + ln, ki1 = ki0 + 16;
    int mv0 = (ki0 < 1000) ? maskp[b * 1000 + ki0] : 0;
    int mv1 = (ki1 < 1000) ? maskp[b * 1000 + ki1] : 0;
#pragma unroll
    for (int reg = 0; reg < 4; ++reg) {
      int qi = qrow + reg;
      float s0 = (mv0 && ki0 <= qi) ? sf[0][reg] * 0.125f : -1.0e30f;
      float s1 = (mv1 && ki1 <= qi) ? sf[1][reg] * 0.125f : -1.0e30f;
      float mx = fmaxf(s0, s1);
#pragma unroll
      for (int d = 1; d < 16; d <<= 1) mx = fmaxf(mx, __shfl_xor(mx, d));
      float mnew = fmaxf(m[reg], mx);
      float sum = __expf(s0 - mnew) + __expf(s1 - mnew);
#pragma unroll
      for (int d = 1; d < 16; d <<= 1) sum += __shfl_xor(sum, d);
      l[reg] = l[reg] * __expf(m[reg] - mnew) + sum;
      m[reg] = mnew;
    }
  }

  float rl[4];
#pragma unroll
  for (int i = 0; i < 4; ++i) rl[i] = 1.0f / l[i];

  f32x4 cacc[4] = {};

  // ---- pass 2: normalized A (f32) + PV ----
  for (int kt = 0; kt < nkt; ++kt) {
    int tok = kt * 32 + kr; if (tok > 999) tok = 999;
    const float* ksrc = Kf + (long)(b * 1000 + tok) * 1024 + h * 64 + ku * 8;
    f32x4 a0 = *(const f32x4*)ksrc;
    f32x4 a1 = *(const f32x4*)(ksrc + 4);
    u16x8 w;
#pragma unroll
    for (int e = 0; e < 4; ++e) { w[e] = f2bf(a0[e]); w[e + 4] = f2bf(a1[e]); }
    u16x8 v8 = *(const u16x8*)(Vb + (long)(b * 1000 + tok) * 1024 + h * 64 + ku * 8);
    __syncthreads();                              // previous tile reads done
    *(u16x8*)&Ks[kr * 72 + ku * 8] = w;
#pragma unroll
    for (int e = 0; e < 8; ++e)                   // transpose V into [d][key]
      Vs[(ku * 8 + e) * 40 + kr] = v8[e];
    __syncthreads();                              // tile staged

    f32x4 sf[2]; computeS(sf);
#pragma unroll
    for (int j = 0; j < 2; ++j) {
      int ki = kt * 32 + j * 16 + ln;
      int mv = (ki < 1000) ? maskp[b * 1000 + ki] : 0;
#pragma unroll
      for (int reg = 0; reg < 4; ++reg) {
        int qi = qrow + reg;
        float p = (mv && ki <= qi) ? __expf(sf[j][reg] * 0.125f - m[reg]) * rl[reg] : 0.f;
        if (qi < 1000 && ki < 1000)
          Aout[((long)bh * 1000 + qi) * 1000 + ki] = p;
        Ps[wid][(4 * lg + reg) * 40 + j * 16 + ln] = f2bf(p);
      }
    }
    __syncthreads();                              // Ps visible (uniform barrier)
    bf16x8 pf = *(const bf16x8*)&Ps[wid][ln * 40 + 8 * lg];
#pragma unroll
    for (int jn = 0; jn < 4; ++jn) {
      bf16x8 vf = *(const bf16x8*)&Vs[(jn * 16 + ln) * 40 + 8 * lg];
      cacc[jn] = __builtin_amdgcn_mfma_f32_16x16x32_bf16(pf, vf, cacc[jn], 0, 0, 0);
    }
  }

#pragma unroll
  for (int jn = 0; jn < 4; ++jn)
#pragma unroll
    for (int reg = 0; reg < 4; ++reg) {
      int qi = qrow + reg;
      if (qi < 1000)
        ctx[(long)(b * 1000 + qi) * 1024 + h * 64 + jn * 16 + ln] = f2bf(cacc[jn][reg]);
    }
}

// ---------------- launch ----------------------------------------------------
extern "C" void kernel_launch(void* const* d_in, const int* in_sizes, int n_in,
                              void* d_out, int out_size, void* d_ws, size_t ws_size,
                              hipStream_t stream)
{
  const float* q  = (const float*)d_in[0];
  const float* k  = (const float*)d_in[1];
  const float* v  = (const float*)d_in[2];
  const int*  msk = (const int*)d_in[3];
  const float* Wq = (const float*)d_in[4];
  const float* bq = (const float*)d_in[5];
  const float* Wk = (const float*)d_in[6];
  const float* bk = (const float*)d_in[7];
  const float* Wv = (const float*)d_in[8];
  const float* bv = (const float*)d_in[9];
  const float* Wp = (const float*)d_in[10];
  const float* bp = (const float*)d_in[11];

  float* Qf = (float*)d_ws;                  // [4000][1024] f32
  float* Kf = Qf + 4096000;                  // [4000][1024] f32
  u16*  Vb  = (u16*)(Kf + 4096000);          // [4000][1024] bf16
  u16*  ctx = Vb + 4096000;                  // [4000][1024] bf16

  float* Xout = (float*)d_out;               // [4000][1024] f32 (output x)
  float* Aout = Xout + 4096000;              // [64][1000][1000] f32 (output A)

  gemm_f32<0, 0><<<dim3(63, 16), 256, 0, stream>>>(q, Wq, bq, Qf, 4000);
  gemm_f32<0, 0><<<dim3(63, 16), 256, 0, stream>>>(k, Wk, bk, Kf, 4000);
  gemm_f32<0, 1><<<dim3(63, 16), 256, 0, stream>>>(v, Wv, bv, Vb, 4000);
  MaskedMultiheadAttention_51591147160164_kernel<<<dim3(16, 64), 256, 0, stream>>>(
      Qf, Kf, Vb, msk, Aout, ctx);
  gemm_f32<1, 0><<<dim3(63, 16), 256, 0, stream>>>(ctx, Wp, bp, Xout, 4000);
}

// Round 10
// 309.319 us; speedup vs baseline: 12.2606x; 2.8740x over previous
//
#include <hip/hip_runtime.h>

typedef unsigned short u16;
typedef __bf16 bf16x8 __attribute__((ext_vector_type(8)));
typedef float f32x4 __attribute__((ext_vector_type(4)));
typedef u16   u16x8 __attribute__((ext_vector_type(8)));

__device__ __forceinline__ u16 f2bf(float f) {
  __bf16 b = (__bf16)f;
  return __builtin_bit_cast(u16, b);
}
__device__ __forceinline__ float bf2f(u16 u) {
  unsigned int x = ((unsigned int)u) << 16;
  return __builtin_bit_cast(float, x);
}

// ---------------- weight f32 -> bf16 conversion (4 matrices of 1024x1024) ----
__global__ __launch_bounds__(256) void convw_kernel(
    const float* __restrict__ w0, const float* __restrict__ w1,
    const float* __restrict__ w2, const float* __restrict__ w3,
    u16* __restrict__ o0, u16* __restrict__ o1,
    u16* __restrict__ o2, u16* __restrict__ o3)
{
  const int z = blockIdx.z;
  const float* s = (z == 0) ? w0 : (z == 1) ? w1 : (z == 2) ? w2 : w3;
  u16* o = (z == 0) ? o0 : (z == 1) ? o1 : (z == 2) ? o2 : o3;
  const long i = ((long)blockIdx.x * 256 + threadIdx.x) * 8;
  f32x4 a = *(const f32x4*)(s + i);
  f32x4 b = *(const f32x4*)(s + i + 4);
  u16x8 r;
#pragma unroll
  for (int e = 0; e < 4; ++e) { r[e] = f2bf(a[e]); r[e + 4] = f2bf(b[e]); }
  *(u16x8*)(o + i) = r;
}

// ---------------- MFMA GEMM: C[m,n] = sum_k A[m,k]*W[n,k] + bias[n] ---------
// A: [rows][1024] f32 (AF32=1, converted at staging) or bf16 (AF32=0).
// Bw: [1024][1024] bf16 (row n = output col n). OUT_F32: C f32 else bf16.
// 128x128 tile, BK=32, 4 waves (each 64x64), 16x16x32 bf16 MFMA.
// Single-buffered LDS, padded rows (stride 40 u16) - pattern validated in attn.
template<int AF32, int OUT_F32>
__global__ __launch_bounds__(256) void gemm_mfma(
    const void* __restrict__ Ap, const u16* __restrict__ Bw,
    const float* __restrict__ bias, void* __restrict__ Cout, int Mvalid)
{
  __shared__ __align__(16) u16 As[128 * 40];
  __shared__ __align__(16) u16 Bs[128 * 40];
  const int tid = threadIdx.x;
  const int wid = tid >> 6, lane = tid & 63, ln = lane & 15, lg = lane >> 4;
  const int row0 = blockIdx.x * 128, col0 = blockIdx.y * 128;
  const int wr = (wid >> 1) * 64, wc = (wid & 1) * 64;
  const int sr = tid >> 1, sh = tid & 1;        // staging: 128 rows x 2 halves
  long arow = row0 + sr; if (arow >= Mvalid) arow = Mvalid - 1;
  const long brow = col0 + sr;

  f32x4 acc[4][4] = {};

  for (int kt = 0; kt < 32; ++kt) {
    const long k0 = (long)kt * 32 + sh * 16;
    u16x8 t0, t1;
    if constexpr (AF32) {
      const float* s = (const float*)Ap + arow * 1024 + k0;
      f32x4 a0 = *(const f32x4*)s;
      f32x4 a1 = *(const f32x4*)(s + 4);
      f32x4 a2 = *(const f32x4*)(s + 8);
      f32x4 a3 = *(const f32x4*)(s + 12);
#pragma unroll
      for (int e = 0; e < 4; ++e) {
        t0[e] = f2bf(a0[e]); t0[e + 4] = f2bf(a1[e]);
        t1[e] = f2bf(a2[e]); t1[e + 4] = f2bf(a3[e]);
      }
    } else {
      const u16x8* s = (const u16x8*)((const u16*)Ap + arow * 1024 + k0);
      t0 = s[0]; t1 = s[1];
    }
    const u16x8* bsrc = (const u16x8*)(Bw + brow * 1024 + k0);
    u16x8 b0 = bsrc[0], b1 = bsrc[1];

    __syncthreads();   // previous iteration's fragment reads complete
    *(u16x8*)&As[sr * 40 + sh * 16    ] = t0;
    *(u16x8*)&As[sr * 40 + sh * 16 + 8] = t1;
    *(u16x8*)&Bs[sr * 40 + sh * 16    ] = b0;
    *(u16x8*)&Bs[sr * 40 + sh * 16 + 8] = b1;
    __syncthreads();   // tile staged

    bf16x8 af[4], bfr[4];
#pragma unroll
    for (int i = 0; i < 4; ++i)
      af[i] = *(const bf16x8*)&As[(wr + i * 16 + ln) * 40 + 8 * lg];
#pragma unroll
    for (int j = 0; j < 4; ++j)
      bfr[j] = *(const bf16x8*)&Bs[(wc + j * 16 + ln) * 40 + 8 * lg];
#pragma unroll
    for (int i = 0; i < 4; ++i)
#pragma unroll
      for (int j = 0; j < 4; ++j)
        acc[i][j] = __builtin_amdgcn_mfma_f32_16x16x32_bf16(af[i], bfr[j], acc[i][j], 0, 0, 0);
  }

  float bj[4];
#pragma unroll
  for (int j = 0; j < 4; ++j) bj[j] = bias[col0 + wc + j * 16 + ln];
#pragma unroll
  for (int i = 0; i < 4; ++i)
#pragma unroll
    for (int j = 0; j < 4; ++j)
#pragma unroll
      for (int reg = 0; reg < 4; ++reg) {
        int r = row0 + wr + i * 16 + 4 * lg + reg;
        int c = col0 + wc + j * 16 + ln;
        if (r < Mvalid) {
          float v = acc[i][j][reg] + bj[j];
          if constexpr (OUT_F32) ((float*)Cout)[(long)r * 1024 + c] = v;
          else                   ((u16*)Cout)[(long)r * 1024 + c] = f2bf(v);
        }
      }
}

// ---------------- MFMA flash attention (bf16 Q/K inputs now) ----------------
// grid (16 qblocks reversed, 64 b*h), 256 thr = 4 waves; wave owns 16 q-rows.
// Qb/Kb/Vb: bf16 [4000][1024]. Two-pass online softmax.
// Aout: f32 [64][1000][1000]. ctx: bf16 [4000][1024].
__global__ __launch_bounds__(256) void MaskedMultiheadAttention_51591147160164_kernel(
    const u16* __restrict__ Qb, const u16* __restrict__ Kb,
    const u16* __restrict__ Vb, const int* __restrict__ maskp,
    float* __restrict__ Aout, u16* __restrict__ ctx)
{
  __shared__ __align__(16) u16 Qs[64 * 72];
  __shared__ __align__(16) u16 Ks[32 * 72];
  __shared__ __align__(16) u16 Vs[64 * 40];      // V^T tile: [d=64][key=32]+pad
  __shared__ __align__(16) u16 Ps[4][16 * 40];   // per-wave P tile [16 q][32 k]+pad

  const int qb = 15 - blockIdx.x;                // heavy blocks dispatch first
  const int bh = blockIdx.y;
  const int b = bh >> 4, h = bh & 15;
  const int q0 = qb * 64;
  const int tid = threadIdx.x;
  const int wid = tid >> 6, lane = tid & 63, ln = lane & 15, lg = lane >> 4;
  const int nkt = 2 * qb + 2;                    // 32-wide k-tiles covering [0, q0+64)

  // ---- stage Q block (64 rows x 64 d) ----
#pragma unroll
  for (int p = 0; p < 2; ++p) {
    int idx = p * 256 + tid;
    int r = idx >> 3, u = idx & 7;
    int tok = q0 + r; if (tok > 999) tok = 999;
    *(u16x8*)&Qs[r * 72 + u * 8] =
        *(const u16x8*)(Qb + (long)(b * 1000 + tok) * 1024 + h * 64 + u * 8);
  }
  __syncthreads();

  bf16x8 qf0, qf1;
  {
    int r = wid * 16 + ln;
    qf0 = *(const bf16x8*)&Qs[r * 72 +      8 * lg];
    qf1 = *(const bf16x8*)&Qs[r * 72 + 32 + 8 * lg];
  }

  const int kr = tid >> 3, ku = tid & 7;         // staging decomposition
  const int qrow = q0 + wid * 16 + 4 * lg;       // + reg = this lane's rows

  auto computeS = [&](f32x4 sf[2]) {
#pragma unroll
    for (int j = 0; j < 2; ++j) {
      int kk = j * 16 + ln;
      bf16x8 kf0 = *(const bf16x8*)&Ks[kk * 72 +      8 * lg];
      bf16x8 kf1 = *(const bf16x8*)&Ks[kk * 72 + 32 + 8 * lg];
      f32x4 z = {0.f, 0.f, 0.f, 0.f};
      z = __builtin_amdgcn_mfma_f32_16x16x32_bf16(qf0, kf0, z, 0, 0, 0);
      z = __builtin_amdgcn_mfma_f32_16x16x32_bf16(qf1, kf1, z, 0, 0, 0);
      sf[j] = z;
    }
  };

  float m[4], l[4];
#pragma unroll
  for (int i = 0; i < 4; ++i) { m[i] = -3.0e38f; l[i] = 0.f; }

  // ---- pass 1: row max + denom ----
  for (int kt = 0; kt < nkt; ++kt) {
    int tok = kt * 32 + kr; if (tok > 999) tok = 999;
    u16x8 w = *(const u16x8*)(Kb + (long)(b * 1000 + tok) * 1024 + h * 64 + ku * 8);
    __syncthreads();                              // previous tile reads done
    *(u16x8*)&Ks[kr * 72 + ku * 8] = w;
    __syncthreads();                              // tile staged

    f32x4 sf[2]; computeS(sf);
    int ki0 = kt * 32 + ln, ki1 = ki0 + 16;
    int mv0 = (ki0 < 1000) ? maskp[b * 1000 + ki0] : 0;
    int mv1 = (ki1 < 1000) ? maskp[b * 1000 + ki1] : 0;
#pragma unroll
    for (int reg = 0; reg < 4; ++reg) {
      int qi = qrow + reg;
      float s0 = (mv0 && ki0 <= qi) ? sf[0][reg] * 0.125f : -1.0e30f;
      float s1 = (mv1 && ki1 <= qi) ? sf[1][reg] * 0.125f : -1.0e30f;
      float mx = fmaxf(s0, s1);
#pragma unroll
      for (int d = 1; d < 16; d <<= 1) mx = fmaxf(mx, __shfl_xor(mx, d));
      float mnew = fmaxf(m[reg], mx);
      float sum = __expf(s0 - mnew) + __expf(s1 - mnew);
#pragma unroll
      for (int d = 1; d < 16; d <<= 1) sum += __shfl_xor(sum, d);
      l[reg] = l[reg] * __expf(m[reg] - mnew) + sum;
      m[reg] = mnew;
    }
  }

  float rl[4];
#pragma unroll
  for (int i = 0; i < 4; ++i) rl[i] = 1.0f / l[i];

  f32x4 cacc[4] = {};

  // ---- pass 2: normalized A (f32) + PV ----
  for (int kt = 0; kt < nkt; ++kt) {
    int tok = kt * 32 + kr; if (tok > 999) tok = 999;
    u16x8 w = *(const u16x8*)(Kb + (long)(b * 1000 + tok) * 1024 + h * 64 + ku * 8);
    u16x8 v8 = *(const u16x8*)(Vb + (long)(b * 1000 + tok) * 1024 + h * 64 + ku * 8);
    __syncthreads();                              // previous tile reads done
    *(u16x8*)&Ks[kr * 72 + ku * 8] = w;
#pragma unroll
    for (int e = 0; e < 8; ++e)                   // transpose V into [d][key]
      Vs[(ku * 8 + e) * 40 + kr] = v8[e];
    __syncthreads();                              // tile staged

    f32x4 sf[2]; computeS(sf);
#pragma unroll
    for (int j = 0; j < 2; ++j) {
      int ki = kt * 32 + j * 16 + ln;
      int mv = (ki < 1000) ? maskp[b * 1000 + ki] : 0;
#pragma unroll
      for (int reg = 0; reg < 4; ++reg) {
        int qi = qrow + reg;
        float p = (mv && ki <= qi) ? __expf(sf[j][reg] * 0.125f - m[reg]) * rl[reg] : 0.f;
        if (qi < 1000 && ki < 1000)
          Aout[((long)bh * 1000 + qi) * 1000 + ki] = p;
        Ps[wid][(4 * lg + reg) * 40 + j * 16 + ln] = f2bf(p);
      }
    }
    __syncthreads();                              // Ps visible (uniform barrier)
    bf16x8 pf = *(const bf16x8*)&Ps[wid][ln * 40 + 8 * lg];
#pragma unroll
    for (int jn = 0; jn < 4; ++jn) {
      bf16x8 vf = *(const bf16x8*)&Vs[(jn * 16 + ln) * 40 + 8 * lg];
      cacc[jn] = __builtin_amdgcn_mfma_f32_16x16x32_bf16(pf, vf, cacc[jn], 0, 0, 0);
    }
  }

#pragma unroll
  for (int jn = 0; jn < 4; ++jn)
#pragma unroll
    for (int reg = 0; reg < 4; ++reg) {
      int qi = qrow + reg;
      if (qi < 1000)
        ctx[(long)(b * 1000 + qi) * 1024 + h * 64 + jn * 16 + ln] = f2bf(cacc[jn][reg]);
    }
}

// ---------------- launch ----------------------------------------------------
extern "C" void kernel_launch(void* const* d_in, const int* in_sizes, int n_in,
                              void* d_out, int out_size, void* d_ws, size_t ws_size,
                              hipStream_t stream)
{
  const float* q  = (const float*)d_in[0];
  const float* k  = (const float*)d_in[1];
  const float* v  = (const float*)d_in[2];
  const int*  msk = (const int*)d_in[3];
  const float* Wq = (const float*)d_in[4];
  const float* bq = (const float*)d_in[5];
  const float* Wk = (const float*)d_in[6];
  const float* bk = (const float*)d_in[7];
  const float* Wv = (const float*)d_in[8];
  const float* bv = (const float*)d_in[9];
  const float* Wp = (const float*)d_in[10];
  const float* bp = (const float*)d_in[11];

  u16* ws  = (u16*)d_ws;                     // 41.2 MB total
  u16* Qb  = ws;                             // [4000][1024] bf16
  u16* Kb  = ws + 4096000u;                  // [4000][1024] bf16
  u16* Vb  = ws + 2u * 4096000u;             // [4000][1024] bf16
  u16* ctx = ws + 3u * 4096000u;             // [4000][1024] bf16
  u16* wqb = ws + 4u * 4096000u;             // [1024][1024] bf16
  u16* wkb = wqb + (1u << 20);
  u16* wvb = wkb + (1u << 20);
  u16* wpb = wvb + (1u << 20);

  float* Xout = (float*)d_out;               // [4000][1024] f32 (output x)
  float* Aout = Xout + 4096000;              // [64][1000][1000] f32 (output A)

  convw_kernel<<<dim3(512, 1, 4), 256, 0, stream>>>(Wq, Wk, Wv, Wp, wqb, wkb, wvb, wpb);
  gemm_mfma<1, 0><<<dim3(32, 8), 256, 0, stream>>>(q, wqb, bq, Qb, 4000);
  gemm_mfma<1, 0><<<dim3(32, 8), 256, 0, stream>>>(k, wkb, bk, Kb, 4000);
  gemm_mfma<1, 0><<<dim3(32, 8), 256, 0, stream>>>(v, wvb, bv, Vb, 4000);
  MaskedMultiheadAttention_51591147160164_kernel<<<dim3(16, 64), 256, 0, stream>>>(
      Qb, Kb, Vb, msk, Aout, ctx);
  gemm_mfma<0, 1><<<dim3(32, 8), 256, 0, stream>>>(ctx, wpb, bp, Xout, 4000);
}

// Round 11
// 252.392 us; speedup vs baseline: 15.0259x; 1.2255x over previous
//
#include <hip/hip_runtime.h>

typedef unsigned short u16;
typedef __bf16 bf16x8 __attribute__((ext_vector_type(8)));
typedef float f32x4 __attribute__((ext_vector_type(4)));
typedef u16   u16x8 __attribute__((ext_vector_type(8)));

__device__ __forceinline__ u16 f2bf(float f) {
  __bf16 b = (__bf16)f;
  return __builtin_bit_cast(u16, b);
}
__device__ __forceinline__ float bf2f(u16 u) {
  unsigned int x = ((unsigned int)u) << 16;
  return __builtin_bit_cast(float, x);
}

// ---------------- weight f32 -> bf16 conversion (4 matrices of 1024x1024) ----
__global__ __launch_bounds__(256) void convw_kernel(
    const float* __restrict__ w0, const float* __restrict__ w1,
    const float* __restrict__ w2, const float* __restrict__ w3,
    u16* __restrict__ o0, u16* __restrict__ o1,
    u16* __restrict__ o2, u16* __restrict__ o3)
{
  const int z = blockIdx.z;
  const float* s = (z == 0) ? w0 : (z == 1) ? w1 : (z == 2) ? w2 : w3;
  u16* o = (z == 0) ? o0 : (z == 1) ? o1 : (z == 2) ? o2 : o3;
  const long i = ((long)blockIdx.x * 256 + threadIdx.x) * 8;
  f32x4 a = *(const f32x4*)(s + i);
  f32x4 b = *(const f32x4*)(s + i + 4);
  u16x8 r;
#pragma unroll
  for (int e = 0; e < 4; ++e) { r[e] = f2bf(a[e]); r[e + 4] = f2bf(b[e]); }
  *(u16x8*)(o + i) = r;
}

// ---------------- MFMA GEMM, 64x128 tile, z-batched -------------------------
// C[m,n] = sum_k A[m,k]*W[n,k] + bias[n]. A: [rows][1024] f32 (AF32=1) or bf16.
// Bw: [1024][1024] bf16 (row n = output col n). blockIdx.z selects (A,B,bias,C)
// triple -> QKV projections fuse into one 1512-block launch (~6 blocks/CU TLP).
// 4 waves, each 32x64 (acc[2][4]); BK=32; single-buffer padded LDS (stride 40).
template<int AF32, int OUT_F32>
__global__ __launch_bounds__(256) void gemm64(
    const void* __restrict__ A0, const void* __restrict__ A1, const void* __restrict__ A2,
    const u16* __restrict__ B0, const u16* __restrict__ B1, const u16* __restrict__ B2,
    const float* __restrict__ g0, const float* __restrict__ g1, const float* __restrict__ g2,
    void* __restrict__ C0, void* __restrict__ C1, void* __restrict__ C2, int Mvalid)
{
  const int z = blockIdx.z;
  const void* Ap = (z == 0) ? A0 : (z == 1) ? A1 : A2;
  const u16* Bw  = (z == 0) ? B0 : (z == 1) ? B1 : B2;
  const float* bias = (z == 0) ? g0 : (z == 1) ? g1 : g2;
  void* Cout = (z == 0) ? C0 : (z == 1) ? C1 : C2;

  __shared__ __align__(16) u16 As[64 * 40];
  __shared__ __align__(16) u16 Bs[128 * 40];
  const int tid = threadIdx.x;
  const int wid = tid >> 6, lane = tid & 63, ln = lane & 15, lg = lane >> 4;
  const int row0 = blockIdx.x * 64, col0 = blockIdx.y * 128;
  const int wr = (wid >> 1) * 32, wc = (wid & 1) * 64;
  const int ar_r = tid >> 2, au = tid & 3;       // A staging: 64 rows x 4 units(8k)
  const int br_r = tid >> 1, bu = tid & 1;       // B staging: 128 rows x 2 units(16k)
  long arow = row0 + ar_r; if (arow >= Mvalid) arow = Mvalid - 1;
  const long brow = col0 + br_r;

  f32x4 acc[2][4] = {};

  for (int kt = 0; kt < 32; ++kt) {
    const long k0 = (long)kt * 32;
    u16x8 ta;
    if constexpr (AF32) {
      const float* s = (const float*)Ap + arow * 1024 + k0 + au * 8;
      f32x4 a0 = *(const f32x4*)s;
      f32x4 a1 = *(const f32x4*)(s + 4);
#pragma unroll
      for (int e = 0; e < 4; ++e) { ta[e] = f2bf(a0[e]); ta[e + 4] = f2bf(a1[e]); }
    } else {
      ta = *(const u16x8*)((const u16*)Ap + arow * 1024 + k0 + au * 8);
    }
    const u16x8* bsrc = (const u16x8*)(Bw + brow * 1024 + k0 + bu * 16);
    u16x8 tb0 = bsrc[0], tb1 = bsrc[1];

    __syncthreads();   // previous iteration's fragment reads complete
    *(u16x8*)&As[ar_r * 40 + au * 8] = ta;
    *(u16x8*)&Bs[br_r * 40 + bu * 16    ] = tb0;
    *(u16x8*)&Bs[br_r * 40 + bu * 16 + 8] = tb1;
    __syncthreads();   // tile staged

    bf16x8 af[2], bfr[4];
#pragma unroll
    for (int i = 0; i < 2; ++i)
      af[i] = *(const bf16x8*)&As[(wr + i * 16 + ln) * 40 + 8 * lg];
#pragma unroll
    for (int j = 0; j < 4; ++j)
      bfr[j] = *(const bf16x8*)&Bs[(wc + j * 16 + ln) * 40 + 8 * lg];
#pragma unroll
    for (int i = 0; i < 2; ++i)
#pragma unroll
      for (int j = 0; j < 4; ++j)
        acc[i][j] = __builtin_amdgcn_mfma_f32_16x16x32_bf16(af[i], bfr[j], acc[i][j], 0, 0, 0);
  }

  float bj[4];
#pragma unroll
  for (int j = 0; j < 4; ++j) bj[j] = bias[col0 + wc + j * 16 + ln];
#pragma unroll
  for (int i = 0; i < 2; ++i)
#pragma unroll
    for (int j = 0; j < 4; ++j)
#pragma unroll
      for (int reg = 0; reg < 4; ++reg) {
        int r = row0 + wr + i * 16 + 4 * lg + reg;
        int c = col0 + wc + j * 16 + ln;
        if (r < Mvalid) {
          float v = acc[i][j][reg] + bj[j];
          if constexpr (OUT_F32) ((float*)Cout)[(long)r * 1024 + c] = v;
          else                   ((u16*)Cout)[(long)r * 1024 + c] = f2bf(v);
        }
      }
}

// ---------------- MFMA flash attention (unchanged from round 10) ------------
__global__ __launch_bounds__(256) void MaskedMultiheadAttention_51591147160164_kernel(
    const u16* __restrict__ Qb, const u16* __restrict__ Kb,
    const u16* __restrict__ Vb, const int* __restrict__ maskp,
    float* __restrict__ Aout, u16* __restrict__ ctx)
{
  __shared__ __align__(16) u16 Qs[64 * 72];
  __shared__ __align__(16) u16 Ks[32 * 72];
  __shared__ __align__(16) u16 Vs[64 * 40];
  __shared__ __align__(16) u16 Ps[4][16 * 40];

  const int qb = 15 - blockIdx.x;
  const int bh = blockIdx.y;
  const int b = bh >> 4, h = bh & 15;
  const int q0 = qb * 64;
  const int tid = threadIdx.x;
  const int wid = tid >> 6, lane = tid & 63, ln = lane & 15, lg = lane >> 4;
  const int nkt = 2 * qb + 2;

#pragma unroll
  for (int p = 0; p < 2; ++p) {
    int idx = p * 256 + tid;
    int r = idx >> 3, u = idx & 7;
    int tok = q0 + r; if (tok > 999) tok = 999;
    *(u16x8*)&Qs[r * 72 + u * 8] =
        *(const u16x8*)(Qb + (long)(b * 1000 + tok) * 1024 + h * 64 + u * 8);
  }
  __syncthreads();

  bf16x8 qf0, qf1;
  {
    int r = wid * 16 + ln;
    qf0 = *(const bf16x8*)&Qs[r * 72 +      8 * lg];
    qf1 = *(const bf16x8*)&Qs[r * 72 + 32 + 8 * lg];
  }

  const int kr = tid >> 3, ku = tid & 7;
  const int qrow = q0 + wid * 16 + 4 * lg;

  auto computeS = [&](f32x4 sf[2]) {
#pragma unroll
    for (int j = 0; j < 2; ++j) {
      int kk = j * 16 + ln;
      bf16x8 kf0 = *(const bf16x8*)&Ks[kk * 72 +      8 * lg];
      bf16x8 kf1 = *(const bf16x8*)&Ks[kk * 72 + 32 + 8 * lg];
      f32x4 zz = {0.f, 0.f, 0.f, 0.f};
      zz = __builtin_amdgcn_mfma_f32_16x16x32_bf16(qf0, kf0, zz, 0, 0, 0);
      zz = __builtin_amdgcn_mfma_f32_16x16x32_bf16(qf1, kf1, zz, 0, 0, 0);
      sf[j] = zz;
    }
  };

  float m[4], l[4];
#pragma unroll
  for (int i = 0; i < 4; ++i) { m[i] = -3.0e38f; l[i] = 0.f; }

  for (int kt = 0; kt < nkt; ++kt) {
    int tok = kt * 32 + kr; if (tok > 999) tok = 999;
    u16x8 w = *(const u16x8*)(Kb + (long)(b * 1000 + tok) * 1024 + h * 64 + ku * 8);
    __syncthreads();
    *(u16x8*)&Ks[kr * 72 + ku * 8] = w;
    __syncthreads();

    f32x4 sf[2]; computeS(sf);
    int ki0 = kt * 32 + ln, ki1 = ki0 + 16;
    int mv0 = (ki0 < 1000) ? maskp[b * 1000 + ki0] : 0;
    int mv1 = (ki1 < 1000) ? maskp[b * 1000 + ki1] : 0;
#pragma unroll
    for (int reg = 0; reg < 4; ++reg) {
      int qi = qrow + reg;
      float s0 = (mv0 && ki0 <= qi) ? sf[0][reg] * 0.125f : -1.0e30f;
      float s1 = (mv1 && ki1 <= qi) ? sf[1][reg] * 0.125f : -1.0e30f;
      float mx = fmaxf(s0, s1);
#pragma unroll
      for (int d = 1; d < 16; d <<= 1) mx = fmaxf(mx, __shfl_xor(mx, d));
      float mnew = fmaxf(m[reg], mx);
      float sum = __expf(s0 - mnew) + __expf(s1 - mnew);
#pragma unroll
      for (int d = 1; d < 16; d <<= 1) sum += __shfl_xor(sum, d);
      l[reg] = l[reg] * __expf(m[reg] - mnew) + sum;
      m[reg] = mnew;
    }
  }

  float rl[4];
#pragma unroll
  for (int i = 0; i < 4; ++i) rl[i] = 1.0f / l[i];

  f32x4 cacc[4] = {};

  for (int kt = 0; kt < nkt; ++kt) {
    int tok = kt * 32 + kr; if (tok > 999) tok = 999;
    u16x8 w = *(const u16x8*)(Kb + (long)(b * 1000 + tok) * 1024 + h * 64 + ku * 8);
    u16x8 v8 = *(const u16x8*)(Vb + (long)(b * 1000 + tok) * 1024 + h * 64 + ku * 8);
    __syncthreads();
    *(u16x8*)&Ks[kr * 72 + ku * 8] = w;
#pragma unroll
    for (int e = 0; e < 8; ++e)
      Vs[(ku * 8 + e) * 40 + kr] = v8[e];
    __syncthreads();

    f32x4 sf[2]; computeS(sf);
#pragma unroll
    for (int j = 0; j < 2; ++j) {
      int ki = kt * 32 + j * 16 + ln;
      int mv = (ki < 1000) ? maskp[b * 1000 + ki] : 0;
#pragma unroll
      for (int reg = 0; reg < 4; ++reg) {
        int qi = qrow + reg;
        float p = (mv && ki <= qi) ? __expf(sf[j][reg] * 0.125f - m[reg]) * rl[reg] : 0.f;
        if (qi < 1000 && ki < 1000)
          Aout[((long)bh * 1000 + qi) * 1000 + ki] = p;
        Ps[wid][(4 * lg + reg) * 40 + j * 16 + ln] = f2bf(p);
      }
    }
    __syncthreads();
    bf16x8 pf = *(const bf16x8*)&Ps[wid][ln * 40 + 8 * lg];
#pragma unroll
    for (int jn = 0; jn < 4; ++jn) {
      bf16x8 vf = *(const bf16x8*)&Vs[(jn * 16 + ln) * 40 + 8 * lg];
      cacc[jn] = __builtin_amdgcn_mfma_f32_16x16x32_bf16(pf, vf, cacc[jn], 0, 0, 0);
    }
  }

#pragma unroll
  for (int jn = 0; jn < 4; ++jn)
#pragma unroll
    for (int reg = 0; reg < 4; ++reg) {
      int qi = qrow + reg;
      if (qi < 1000)
        ctx[(long)(b * 1000 + qi) * 1024 + h * 64 + jn * 16 + ln] = f2bf(cacc[jn][reg]);
    }
}

// ---------------- launch ----------------------------------------------------
extern "C" void kernel_launch(void* const* d_in, const int* in_sizes, int n_in,
                              void* d_out, int out_size, void* d_ws, size_t ws_size,
                              hipStream_t stream)
{
  const float* q  = (const float*)d_in[0];
  const float* k  = (const float*)d_in[1];
  const float* v  = (const float*)d_in[2];
  const int*  msk = (const int*)d_in[3];
  const float* Wq = (const float*)d_in[4];
  const float* bq = (const float*)d_in[5];
  const float* Wk = (const float*)d_in[6];
  const float* bk = (const float*)d_in[7];
  const float* Wv = (const float*)d_in[8];
  const float* bv = (const float*)d_in[9];
  const float* Wp = (const float*)d_in[10];
  const float* bp = (const float*)d_in[11];

  u16* ws  = (u16*)d_ws;                     // 41.2 MB total
  u16* Qb  = ws;                             // [4000][1024] bf16
  u16* Kb  = ws + 4096000u;                  // [4000][1024] bf16
  u16* Vb  = ws + 2u * 4096000u;             // [4000][1024] bf16
  u16* ctx = ws + 3u * 4096000u;             // [4000][1024] bf16
  u16* wqb = ws + 4u * 4096000u;             // [1024][1024] bf16
  u16* wkb = wqb + (1u << 20);
  u16* wvb = wkb + (1u << 20);
  u16* wpb = wvb + (1u << 20);

  float* Xout = (float*)d_out;               // [4000][1024] f32 (output x)
  float* Aout = Xout + 4096000;              // [64][1000][1000] f32 (output A)

  convw_kernel<<<dim3(512, 1, 4), 256, 0, stream>>>(Wq, Wk, Wv, Wp, wqb, wkb, wvb, wpb);
  // fused QKV projections: grid (63, 8, 3) = 1512 blocks (~6 blocks/CU)
  gemm64<1, 0><<<dim3(63, 8, 3), 256, 0, stream>>>(
      q, k, v, wqb, wkb, wvb, bq, bk, bv, Qb, Kb, Vb, 4000);
  MaskedMultiheadAttention_51591147160164_kernel<<<dim3(16, 64), 256, 0, stream>>>(
      Qb, Kb, Vb, msk, Aout, ctx);
  // output projection: grid (63, 8) = 504 blocks (~2 blocks/CU)
  gemm64<0, 1><<<dim3(63, 8, 1), 256, 0, stream>>>(
      ctx, ctx, ctx, wpb, wpb, wpb, bp, bp, bp, Xout, Xout, Xout, 4000);
}

// Round 12
// 222.252 us; speedup vs baseline: 17.0636x; 1.1356x over previous
//
#include <hip/hip_runtime.h>

typedef unsigned short u16;
typedef __bf16 bf16x8 __attribute__((ext_vector_type(8)));
typedef float f32x4 __attribute__((ext_vector_type(4)));
typedef u16   u16x8 __attribute__((ext_vector_type(8)));

__device__ __forceinline__ u16 f2bf(float f) {
  __bf16 b = (__bf16)f;
  return __builtin_bit_cast(u16, b);
}
__device__ __forceinline__ float bf2f(u16 u) {
  unsigned int x = ((unsigned int)u) << 16;
  return __builtin_bit_cast(float, x);
}

// async global->LDS, 16B per lane. LDS dest: wave-uniform base + lane*16.
__device__ __forceinline__ void gll16(const u16* g, u16* l) {
  __builtin_amdgcn_global_load_lds(
      (const __attribute__((address_space(1))) void*)g,
      (__attribute__((address_space(3))) void*)l, 16, 0, 0);
}

// ---------------- f32 -> bf16 conversion kernels ----------------------------
__global__ __launch_bounds__(256) void convw_kernel(
    const float* __restrict__ w0, const float* __restrict__ w1,
    const float* __restrict__ w2, const float* __restrict__ w3,
    u16* __restrict__ o0, u16* __restrict__ o1,
    u16* __restrict__ o2, u16* __restrict__ o3)
{
  const int z = blockIdx.z;
  const float* s = (z == 0) ? w0 : (z == 1) ? w1 : (z == 2) ? w2 : w3;
  u16* o = (z == 0) ? o0 : (z == 1) ? o1 : (z == 2) ? o2 : o3;
  const long i = ((long)blockIdx.x * 256 + threadIdx.x) * 8;
  f32x4 a = *(const f32x4*)(s + i);
  f32x4 b = *(const f32x4*)(s + i + 4);
  u16x8 r;
#pragma unroll
  for (int e = 0; e < 4; ++e) { r[e] = f2bf(a[e]); r[e + 4] = f2bf(b[e]); }
  *(u16x8*)(o + i) = r;
}

__global__ __launch_bounds__(256) void convact_kernel(
    const float* __restrict__ a0, const float* __restrict__ a1,
    const float* __restrict__ a2,
    u16* __restrict__ o0, u16* __restrict__ o1, u16* __restrict__ o2)
{
  const int z = blockIdx.z;
  const float* s = (z == 0) ? a0 : (z == 1) ? a1 : a2;
  u16* o = (z == 0) ? o0 : (z == 1) ? o1 : o2;
  const long i = ((long)blockIdx.x * 256 + threadIdx.x) * 8;
  f32x4 a = *(const f32x4*)(s + i);
  f32x4 b = *(const f32x4*)(s + i + 4);
  u16x8 r;
#pragma unroll
  for (int e = 0; e < 4; ++e) { r[e] = f2bf(a[e]); r[e + 4] = f2bf(b[e]); }
  *(u16x8*)(o + i) = r;
}

// ---------------- MFMA GEMM, m97 structure (global_load_lds staging) --------
// C[m,n] = sum_k A[m,k]*W[n,k] + bias[n]. A: [rows][1024] bf16.
// Bw: [1024][1024] bf16 (row n = output col n). BM x 128 tile, BK=32.
// 4 waves; BM=128: wave=64x64 acc[4][4]; BM=64: wave=32x64 acc[2][4].
// Linear LDS [rows][32] bf16 (64B rows); 2 barriers/K-step; z-batched operands.
template<int BM, int OUT_F32>
__global__ __launch_bounds__(256) void gemm_gll(
    const u16* __restrict__ A0, const u16* __restrict__ A1, const u16* __restrict__ A2,
    const u16* __restrict__ B0, const u16* __restrict__ B1, const u16* __restrict__ B2,
    const float* __restrict__ g0, const float* __restrict__ g1, const float* __restrict__ g2,
    void* __restrict__ C0, void* __restrict__ C1, void* __restrict__ C2, int Mvalid)
{
  constexpr int ACH = BM / 64;            // A staging chunks per wave (1KB each)
  constexpr int MI  = BM / 32;            // M fragments per wave
  const int z = blockIdx.z;
  const u16* Ab = (z == 0) ? A0 : (z == 1) ? A1 : A2;
  const u16* Bw = (z == 0) ? B0 : (z == 1) ? B1 : B2;
  const float* bias = (z == 0) ? g0 : (z == 1) ? g1 : g2;
  void* Cout = (z == 0) ? C0 : (z == 1) ? C1 : C2;

  __shared__ __align__(16) u16 As[BM * 32];
  __shared__ __align__(16) u16 Bs[128 * 32];

  const int tid = threadIdx.x;
  const int wid = tid >> 6, lane = tid & 63, ln = lane & 15, lg = lane >> 4;
  const int row0 = blockIdx.x * BM, col0 = blockIdx.y * 128;
  const int wr = (wid >> 1) * (BM / 2), wc = (wid & 1) * 64;
  const int lr4 = lane >> 2, kq = lane & 3;   // staging: 16 rows x 4 k-quarters

  f32x4 acc[MI][4] = {};

  for (int kt = 0; kt < 32; ++kt) {
    const int k0 = kt * 32;
    __syncthreads();                          // previous tile's reads complete
#pragma unroll
    for (int c = 0; c < ACH; ++c) {
      int lr = wid * (16 * ACH) + c * 16 + lr4;
      long gr = row0 + lr; if (gr >= Mvalid) gr = Mvalid - 1;
      gll16(Ab + gr * 1024 + k0 + kq * 8, &As[(wid * (16 * ACH) + c * 16) * 32]);
    }
#pragma unroll
    for (int c = 0; c < 2; ++c) {
      int lr = wid * 32 + c * 16 + lr4;
      gll16(Bw + (long)(col0 + lr) * 1024 + k0 + kq * 8, &Bs[(wid * 32 + c * 16) * 32]);
    }
    __syncthreads();                          // barrier drains vmcnt -> tile staged

    bf16x8 af[MI], bfr[4];
#pragma unroll
    for (int i = 0; i < MI; ++i)
      af[i] = *(const bf16x8*)&As[(wr + i * 16 + ln) * 32 + 8 * lg];
#pragma unroll
    for (int j = 0; j < 4; ++j)
      bfr[j] = *(const bf16x8*)&Bs[(wc + j * 16 + ln) * 32 + 8 * lg];
#pragma unroll
    for (int i = 0; i < MI; ++i)
#pragma unroll
      for (int j = 0; j < 4; ++j)
        acc[i][j] = __builtin_amdgcn_mfma_f32_16x16x32_bf16(af[i], bfr[j], acc[i][j], 0, 0, 0);
  }

  float bj[4];
#pragma unroll
  for (int j = 0; j < 4; ++j) bj[j] = bias[col0 + wc + j * 16 + ln];
#pragma unroll
  for (int i = 0; i < MI; ++i)
#pragma unroll
    for (int j = 0; j < 4; ++j)
#pragma unroll
      for (int reg = 0; reg < 4; ++reg) {
        int r = row0 + wr + i * 16 + 4 * lg + reg;
        int c = col0 + wc + j * 16 + ln;
        if (r < Mvalid) {
          float v = acc[i][j][reg] + bj[j];
          if constexpr (OUT_F32) ((float*)Cout)[(long)r * 1024 + c] = v;
          else                   ((u16*)Cout)[(long)r * 1024 + c] = f2bf(v);
        }
      }
}

// ---------------- MFMA flash attention (unchanged, green since round 9) -----
__global__ __launch_bounds__(256) void MaskedMultiheadAttention_51591147160164_kernel(
    const u16* __restrict__ Qb, const u16* __restrict__ Kb,
    const u16* __restrict__ Vb, const int* __restrict__ maskp,
    float* __restrict__ Aout, u16* __restrict__ ctx)
{
  __shared__ __align__(16) u16 Qs[64 * 72];
  __shared__ __align__(16) u16 Ks[32 * 72];
  __shared__ __align__(16) u16 Vs[64 * 40];
  __shared__ __align__(16) u16 Ps[4][16 * 40];

  const int qb = 15 - blockIdx.x;
  const int bh = blockIdx.y;
  const int b = bh >> 4, h = bh & 15;
  const int q0 = qb * 64;
  const int tid = threadIdx.x;
  const int wid = tid >> 6, lane = tid & 63, ln = lane & 15, lg = lane >> 4;
  const int nkt = 2 * qb + 2;

#pragma unroll
  for (int p = 0; p < 2; ++p) {
    int idx = p * 256 + tid;
    int r = idx >> 3, u = idx & 7;
    int tok = q0 + r; if (tok > 999) tok = 999;
    *(u16x8*)&Qs[r * 72 + u * 8] =
        *(const u16x8*)(Qb + (long)(b * 1000 + tok) * 1024 + h * 64 + u * 8);
  }
  __syncthreads();

  bf16x8 qf0, qf1;
  {
    int r = wid * 16 + ln;
    qf0 = *(const bf16x8*)&Qs[r * 72 +      8 * lg];
    qf1 = *(const bf16x8*)&Qs[r * 72 + 32 + 8 * lg];
  }

  const int kr = tid >> 3, ku = tid & 7;
  const int qrow = q0 + wid * 16 + 4 * lg;

  auto computeS = [&](f32x4 sf[2]) {
#pragma unroll
    for (int j = 0; j < 2; ++j) {
      int kk = j * 16 + ln;
      bf16x8 kf0 = *(const bf16x8*)&Ks[kk * 72 +      8 * lg];
      bf16x8 kf1 = *(const bf16x8*)&Ks[kk * 72 + 32 + 8 * lg];
      f32x4 zz = {0.f, 0.f, 0.f, 0.f};
      zz = __builtin_amdgcn_mfma_f32_16x16x32_bf16(qf0, kf0, zz, 0, 0, 0);
      zz = __builtin_amdgcn_mfma_f32_16x16x32_bf16(qf1, kf1, zz, 0, 0, 0);
      sf[j] = zz;
    }
  };

  float m[4], l[4];
#pragma unroll
  for (int i = 0; i < 4; ++i) { m[i] = -3.0e38f; l[i] = 0.f; }

  for (int kt = 0; kt < nkt; ++kt) {
    int tok = kt * 32 + kr; if (tok > 999) tok = 999;
    u16x8 w = *(const u16x8*)(Kb + (long)(b * 1000 + tok) * 1024 + h * 64 + ku * 8);
    __syncthreads();
    *(u16x8*)&Ks[kr * 72 + ku * 8] = w;
    __syncthreads();

    f32x4 sf[2]; computeS(sf);
    int ki0 = kt * 32 + ln, ki1 = ki0 + 16;
    int mv0 = (ki0 < 1000) ? maskp[b * 1000 + ki0] : 0;
    int mv1 = (ki1 < 1000) ? maskp[b * 1000 + ki1] : 0;
#pragma unroll
    for (int reg = 0; reg < 4; ++reg) {
      int qi = qrow + reg;
      float s0 = (mv0 && ki0 <= qi) ? sf[0][reg] * 0.125f : -1.0e30f;
      float s1 = (mv1 && ki1 <= qi) ? sf[1][reg] * 0.125f : -1.0e30f;
      float mx = fmaxf(s0, s1);
#pragma unroll
      for (int d = 1; d < 16; d <<= 1) mx = fmaxf(mx, __shfl_xor(mx, d));
      float mnew = fmaxf(m[reg], mx);
      float sum = __expf(s0 - mnew) + __expf(s1 - mnew);
#pragma unroll
      for (int d = 1; d < 16; d <<= 1) sum += __shfl_xor(sum, d);
      l[reg] = l[reg] * __expf(m[reg] - mnew) + sum;
      m[reg] = mnew;
    }
  }

  float rl[4];
#pragma unroll
  for (int i = 0; i < 4; ++i) rl[i] = 1.0f / l[i];

  f32x4 cacc[4] = {};

  for (int kt = 0; kt < nkt; ++kt) {
    int tok = kt * 32 + kr; if (tok > 999) tok = 999;
    u16x8 w = *(const u16x8*)(Kb + (long)(b * 1000 + tok) * 1024 + h * 64 + ku * 8);
    u16x8 v8 = *(const u16x8*)(Vb + (long)(b * 1000 + tok) * 1024 + h * 64 + ku * 8);
    __syncthreads();
    *(u16x8*)&Ks[kr * 72 + ku * 8] = w;
#pragma unroll
    for (int e = 0; e < 8; ++e)
      Vs[(ku * 8 + e) * 40 + kr] = v8[e];
    __syncthreads();

    f32x4 sf[2]; computeS(sf);
#pragma unroll
    for (int j = 0; j < 2; ++j) {
      int ki = kt * 32 + j * 16 + ln;
      int mv = (ki < 1000) ? maskp[b * 1000 + ki] : 0;
#pragma unroll
      for (int reg = 0; reg < 4; ++reg) {
        int qi = qrow + reg;
        float p = (mv && ki <= qi) ? __expf(sf[j][reg] * 0.125f - m[reg]) * rl[reg] : 0.f;
        if (qi < 1000 && ki < 1000)
          Aout[((long)bh * 1000 + qi) * 1000 + ki] = p;
        Ps[wid][(4 * lg + reg) * 40 + j * 16 + ln] = f2bf(p);
      }
    }
    __syncthreads();
    bf16x8 pf = *(const bf16x8*)&Ps[wid][ln * 40 + 8 * lg];
#pragma unroll
    for (int jn = 0; jn < 4; ++jn) {
      bf16x8 vf = *(const bf16x8*)&Vs[(jn * 16 + ln) * 40 + 8 * lg];
      cacc[jn] = __builtin_amdgcn_mfma_f32_16x16x32_bf16(pf, vf, cacc[jn], 0, 0, 0);
    }
  }

#pragma unroll
  for (int jn = 0; jn < 4; ++jn)
#pragma unroll
    for (int reg = 0; reg < 4; ++reg) {
      int qi = qrow + reg;
      if (qi < 1000)
        ctx[(long)(b * 1000 + qi) * 1024 + h * 64 + jn * 16 + ln] = f2bf(cacc[jn][reg]);
    }
}

// ---------------- launch ----------------------------------------------------
extern "C" void kernel_launch(void* const* d_in, const int* in_sizes, int n_in,
                              void* d_out, int out_size, void* d_ws, size_t ws_size,
                              hipStream_t stream)
{
  const float* q  = (const float*)d_in[0];
  const float* k  = (const float*)d_in[1];
  const float* v  = (const float*)d_in[2];
  const int*  msk = (const int*)d_in[3];
  const float* Wq = (const float*)d_in[4];
  const float* bq = (const float*)d_in[5];
  const float* Wk = (const float*)d_in[6];
  const float* bk = (const float*)d_in[7];
  const float* Wv = (const float*)d_in[8];
  const float* bv = (const float*)d_in[9];
  const float* Wp = (const float*)d_in[10];
  const float* bp = (const float*)d_in[11];

  u16* ws  = (u16*)d_ws;                     // 56 MB total
  u16* Qc  = ws;                             // [4000][1024] bf16 (q cast; ctx aliases later)
  u16* Kc  = ws + 4096000u;                  // [4000][1024] bf16 (k cast)
  u16* Vc  = ws + 2u * 4096000u;             // [4000][1024] bf16 (v cast)
  u16* Qb  = ws + 3u * 4096000u;             // [4000][1024] bf16 (Q proj)
  u16* Kb  = ws + 4u * 4096000u;             // [4000][1024] bf16 (K proj)
  u16* Vb  = ws + 5u * 4096000u;             // [4000][1024] bf16 (V proj)
  u16* wqb = ws + 6u * 4096000u;             // [1024][1024] bf16
  u16* wkb = wqb + (1u << 20);
  u16* wvb = wkb + (1u << 20);
  u16* wpb = wvb + (1u << 20);
  u16* ctx = Qc;                             // alias: Qc dead after QKV GEMM

  float* Xout = (float*)d_out;               // [4000][1024] f32 (output x)
  float* Aout = Xout + 4096000;              // [64][1000][1000] f32 (output A)

  convw_kernel<<<dim3(512, 1, 4), 256, 0, stream>>>(Wq, Wk, Wv, Wp, wqb, wkb, wvb, wpb);
  convact_kernel<<<dim3(2000, 1, 3), 256, 0, stream>>>(q, k, v, Qc, Kc, Vc);
  // fused QKV projections: 128x128 tiles, grid (32,8,3)=768 blocks (3/CU)
  gemm_gll<128, 0><<<dim3(32, 8, 3), 256, 0, stream>>>(
      Qc, Kc, Vc, wqb, wkb, wvb, bq, bk, bv, Qb, Kb, Vb, 4000);
  MaskedMultiheadAttention_51591147160164_kernel<<<dim3(16, 64), 256, 0, stream>>>(
      Qb, Kb, Vb, msk, Aout, ctx);
  // output projection: 64x128 tiles, grid (63,8)=504 blocks (2/CU)
  gemm_gll<64, 1><<<dim3(63, 8, 1), 256, 0, stream>>>(
      ctx, ctx, ctx, wpb, wpb, wpb, bp, bp, bp, Xout, Xout, Xout, 4000);
}

// Round 13
// 217.031 us; speedup vs baseline: 17.4741x; 1.0241x over previous
//
#include <hip/hip_runtime.h>

typedef unsigned short u16;
typedef __bf16 bf16x8 __attribute__((ext_vector_type(8)));
typedef float f32x4 __attribute__((ext_vector_type(4)));
typedef u16   u16x8 __attribute__((ext_vector_type(8)));

__device__ __forceinline__ u16 f2bf(float f) {
  __bf16 b = (__bf16)f;
  return __builtin_bit_cast(u16, b);
}
__device__ __forceinline__ float bf2f(u16 u) {
  unsigned int x = ((unsigned int)u) << 16;
  return __builtin_bit_cast(float, x);
}

// async global->LDS, 16B per lane. LDS dest: wave-uniform base + lane*16.
__device__ __forceinline__ void gll16(const u16* g, u16* l) {
  __builtin_amdgcn_global_load_lds(
      (const __attribute__((address_space(1))) void*)g,
      (__attribute__((address_space(3))) void*)l, 16, 0, 0);
}

// ---------------- f32 -> bf16 conversion kernels ----------------------------
__global__ __launch_bounds__(256) void convw_kernel(
    const float* __restrict__ w0, const float* __restrict__ w1,
    const float* __restrict__ w2, const float* __restrict__ w3,
    u16* __restrict__ o0, u16* __restrict__ o1,
    u16* __restrict__ o2, u16* __restrict__ o3)
{
  const int z = blockIdx.z;
  const float* s = (z == 0) ? w0 : (z == 1) ? w1 : (z == 2) ? w2 : w3;
  u16* o = (z == 0) ? o0 : (z == 1) ? o1 : (z == 2) ? o2 : o3;
  const long i = ((long)blockIdx.x * 256 + threadIdx.x) * 8;
  f32x4 a = *(const f32x4*)(s + i);
  f32x4 b = *(const f32x4*)(s + i + 4);
  u16x8 r;
#pragma unroll
  for (int e = 0; e < 4; ++e) { r[e] = f2bf(a[e]); r[e + 4] = f2bf(b[e]); }
  *(u16x8*)(o + i) = r;
}

__global__ __launch_bounds__(256) void convact_kernel(
    const float* __restrict__ a0, const float* __restrict__ a1,
    const float* __restrict__ a2,
    u16* __restrict__ o0, u16* __restrict__ o1, u16* __restrict__ o2)
{
  const int z = blockIdx.z;
  const float* s = (z == 0) ? a0 : (z == 1) ? a1 : a2;
  u16* o = (z == 0) ? o0 : (z == 1) ? o1 : o2;
  const long i = ((long)blockIdx.x * 256 + threadIdx.x) * 8;
  f32x4 a = *(const f32x4*)(s + i);
  f32x4 b = *(const f32x4*)(s + i + 4);
  u16x8 r;
#pragma unroll
  for (int e = 0; e < 4; ++e) { r[e] = f2bf(a[e]); r[e + 4] = f2bf(b[e]); }
  *(u16x8*)(o + i) = r;
}

// ---------------- MFMA GEMM: BK=64, swizzled LDS via pre-swizzled source ----
// C[m,n] = sum_k A[m,k]*W[n,k] + bias[n]. A: [rows][1024] bf16.
// Bw: [1024][1024] bf16 (row n = output col n). BM x 128 tile, BK=64, 16 K-steps.
// LDS rows 128B. Staging: linear dest, source col pre-swizzled
//   col = k0 + 8*((lane&7)^(lane>>3))  ->  LDS(row, 8t) holds col k0+8*(t^(row&7)).
// Fragment read offset: (kk+8*lg) ^ ((r&7)<<3)  -> conflict-free (2 lanes/bank).
// 4 waves; 32 MFMA per wave per K-step; 3 blocks/CU guaranteed by launch_bounds.
template<int BM, int OUT_F32>
__global__ __launch_bounds__(256, 3) void gemm_swz(
    const u16* __restrict__ A0, const u16* __restrict__ A1, const u16* __restrict__ A2,
    const u16* __restrict__ B0, const u16* __restrict__ B1, const u16* __restrict__ B2,
    const float* __restrict__ g0, const float* __restrict__ g1, const float* __restrict__ g2,
    void* __restrict__ C0, void* __restrict__ C1, void* __restrict__ C2, int Mvalid)
{
  constexpr int ACH = BM / 32;            // A wave-loads (8 rows each) per wave
  constexpr int MI  = BM / 32;            // M fragments per wave
  const int z = blockIdx.z;
  const u16* Ab = (z == 0) ? A0 : (z == 1) ? A1 : A2;
  const u16* Bw = (z == 0) ? B0 : (z == 1) ? B1 : B2;
  const float* bias = (z == 0) ? g0 : (z == 1) ? g1 : g2;
  void* Cout = (z == 0) ? C0 : (z == 1) ? C1 : C2;

  __shared__ __align__(16) u16 As[BM * 64];
  __shared__ __align__(16) u16 Bs[128 * 64];

  const int tid = threadIdx.x;
  const int wid = tid >> 6, lane = tid & 63, ln = lane & 15, lg = lane >> 4;
  const int row0 = blockIdx.x * BM, col0 = blockIdx.y * 128;
  const int wr = (wid >> 1) * (BM / 2), wc = (wid & 1) * 64;
  const int lr8 = lane >> 3;                       // row within 8-row group
  const int kslot = 8 * ((lane & 7) ^ lr8);        // pre-swizzled source k-offset

  f32x4 acc[MI][4] = {};

  for (int kt = 0; kt < 16; ++kt) {
    const int k0 = kt * 64;
    __syncthreads();                               // previous tile's reads done
#pragma unroll
    for (int c = 0; c < ACH; ++c) {
      int base = wid * (8 * ACH) + c * 8;          // 8 A rows per wave-load
      long gr = row0 + base + lr8; if (gr >= Mvalid) gr = Mvalid - 1;
      gll16(Ab + gr * 1024 + k0 + kslot, &As[base * 64]);
    }
#pragma unroll
    for (int c = 0; c < 4; ++c) {
      int base = wid * 32 + c * 8;                 // 8 B rows per wave-load
      gll16(Bw + (long)(col0 + base + lr8) * 1024 + k0 + kslot, &Bs[base * 64]);
    }
    __syncthreads();                               // barrier drains vmcnt

#pragma unroll
    for (int kk = 0; kk < 64; kk += 32) {
      bf16x8 af[MI], bfr[4];
#pragma unroll
      for (int i = 0; i < MI; ++i) {
        int r = wr + i * 16 + ln;
        af[i] = *(const bf16x8*)&As[r * 64 + ((kk + 8 * lg) ^ ((r & 7) << 3))];
      }
#pragma unroll
      for (int j = 0; j < 4; ++j) {
        int r = wc + j * 16 + ln;
        bfr[j] = *(const bf16x8*)&Bs[r * 64 + ((kk + 8 * lg) ^ ((r & 7) << 3))];
      }
#pragma unroll
      for (int i = 0; i < MI; ++i)
#pragma unroll
        for (int j = 0; j < 4; ++j)
          acc[i][j] = __builtin_amdgcn_mfma_f32_16x16x32_bf16(af[i], bfr[j], acc[i][j], 0, 0, 0);
    }
  }

  float bj[4];
#pragma unroll
  for (int j = 0; j < 4; ++j) bj[j] = bias[col0 + wc + j * 16 + ln];
#pragma unroll
  for (int i = 0; i < MI; ++i)
#pragma unroll
    for (int j = 0; j < 4; ++j)
#pragma unroll
      for (int reg = 0; reg < 4; ++reg) {
        int r = row0 + wr + i * 16 + 4 * lg + reg;
        int c = col0 + wc + j * 16 + ln;
        if (r < Mvalid) {
          float v = acc[i][j][reg] + bj[j];
          if constexpr (OUT_F32) ((float*)Cout)[(long)r * 1024 + c] = v;
          else                   ((u16*)Cout)[(long)r * 1024 + c] = f2bf(v);
        }
      }
}

// ---------------- MFMA flash attention (unchanged, green since round 9) -----
__global__ __launch_bounds__(256) void MaskedMultiheadAttention_51591147160164_kernel(
    const u16* __restrict__ Qb, const u16* __restrict__ Kb,
    const u16* __restrict__ Vb, const int* __restrict__ maskp,
    float* __restrict__ Aout, u16* __restrict__ ctx)
{
  __shared__ __align__(16) u16 Qs[64 * 72];
  __shared__ __align__(16) u16 Ks[32 * 72];
  __shared__ __align__(16) u16 Vs[64 * 40];
  __shared__ __align__(16) u16 Ps[4][16 * 40];

  const int qb = 15 - blockIdx.x;
  const int bh = blockIdx.y;
  const int b = bh >> 4, h = bh & 15;
  const int q0 = qb * 64;
  const int tid = threadIdx.x;
  const int wid = tid >> 6, lane = tid & 63, ln = lane & 15, lg = lane >> 4;
  const int nkt = 2 * qb + 2;

#pragma unroll
  for (int p = 0; p < 2; ++p) {
    int idx = p * 256 + tid;
    int r = idx >> 3, u = idx & 7;
    int tok = q0 + r; if (tok > 999) tok = 999;
    *(u16x8*)&Qs[r * 72 + u * 8] =
        *(const u16x8*)(Qb + (long)(b * 1000 + tok) * 1024 + h * 64 + u * 8);
  }
  __syncthreads();

  bf16x8 qf0, qf1;
  {
    int r = wid * 16 + ln;
    qf0 = *(const bf16x8*)&Qs[r * 72 +      8 * lg];
    qf1 = *(const bf16x8*)&Qs[r * 72 + 32 + 8 * lg];
  }

  const int kr = tid >> 3, ku = tid & 7;
  const int qrow = q0 + wid * 16 + 4 * lg;

  auto computeS = [&](f32x4 sf[2]) {
#pragma unroll
    for (int j = 0; j < 2; ++j) {
      int kk = j * 16 + ln;
      bf16x8 kf0 = *(const bf16x8*)&Ks[kk * 72 +      8 * lg];
      bf16x8 kf1 = *(const bf16x8*)&Ks[kk * 72 + 32 + 8 * lg];
      f32x4 zz = {0.f, 0.f, 0.f, 0.f};
      zz = __builtin_amdgcn_mfma_f32_16x16x32_bf16(qf0, kf0, zz, 0, 0, 0);
      zz = __builtin_amdgcn_mfma_f32_16x16x32_bf16(qf1, kf1, zz, 0, 0, 0);
      sf[j] = zz;
    }
  };

  float m[4], l[4];
#pragma unroll
  for (int i = 0; i < 4; ++i) { m[i] = -3.0e38f; l[i] = 0.f; }

  for (int kt = 0; kt < nkt; ++kt) {
    int tok = kt * 32 + kr; if (tok > 999) tok = 999;
    u16x8 w = *(const u16x8*)(Kb + (long)(b * 1000 + tok) * 1024 + h * 64 + ku * 8);
    __syncthreads();
    *(u16x8*)&Ks[kr * 72 + ku * 8] = w;
    __syncthreads();

    f32x4 sf[2]; computeS(sf);
    int ki0 = kt * 32 + ln, ki1 = ki0 + 16;
    int mv0 = (ki0 < 1000) ? maskp[b * 1000 + ki0] : 0;
    int mv1 = (ki1 < 1000) ? maskp[b * 1000 + ki1] : 0;
#pragma unroll
    for (int reg = 0; reg < 4; ++reg) {
      int qi = qrow + reg;
      float s0 = (mv0 && ki0 <= qi) ? sf[0][reg] * 0.125f : -1.0e30f;
      float s1 = (mv1 && ki1 <= qi) ? sf[1][reg] * 0.125f : -1.0e30f;
      float mx = fmaxf(s0, s1);
#pragma unroll
      for (int d = 1; d < 16; d <<= 1) mx = fmaxf(mx, __shfl_xor(mx, d));
      float mnew = fmaxf(m[reg], mx);
      float sum = __expf(s0 - mnew) + __expf(s1 - mnew);
#pragma unroll
      for (int d = 1; d < 16; d <<= 1) sum += __shfl_xor(sum, d);
      l[reg] = l[reg] * __expf(m[reg] - mnew) + sum;
      m[reg] = mnew;
    }
  }

  float rl[4];
#pragma unroll
  for (int i = 0; i < 4; ++i) rl[i] = 1.0f / l[i];

  f32x4 cacc[4] = {};

  for (int kt = 0; kt < nkt; ++kt) {
    int tok = kt * 32 + kr; if (tok > 999) tok = 999;
    u16x8 w = *(const u16x8*)(Kb + (long)(b * 1000 + tok) * 1024 + h * 64 + ku * 8);
    u16x8 v8 = *(const u16x8*)(Vb + (long)(b * 1000 + tok) * 1024 + h * 64 + ku * 8);
    __syncthreads();
    *(u16x8*)&Ks[kr * 72 + ku * 8] = w;
#pragma unroll
    for (int e = 0; e < 8; ++e)
      Vs[(ku * 8 + e) * 40 + kr] = v8[e];
    __syncthreads();

    f32x4 sf[2]; computeS(sf);
#pragma unroll
    for (int j = 0; j < 2; ++j) {
      int ki = kt * 32 + j * 16 + ln;
      int mv = (ki < 1000) ? maskp[b * 1000 + ki] : 0;
#pragma unroll
      for (int reg = 0; reg < 4; ++reg) {
        int qi = qrow + reg;
        float p = (mv && ki <= qi) ? __expf(sf[j][reg] * 0.125f - m[reg]) * rl[reg] : 0.f;
        if (qi < 1000 && ki < 1000)
          Aout[((long)bh * 1000 + qi) * 1000 + ki] = p;
        Ps[wid][(4 * lg + reg) * 40 + j * 16 + ln] = f2bf(p);
      }
    }
    __syncthreads();
    bf16x8 pf = *(const bf16x8*)&Ps[wid][ln * 40 + 8 * lg];
#pragma unroll
    for (int jn = 0; jn < 4; ++jn) {
      bf16x8 vf = *(const bf16x8*)&Vs[(jn * 16 + ln) * 40 + 8 * lg];
      cacc[jn] = __builtin_amdgcn_mfma_f32_16x16x32_bf16(pf, vf, cacc[jn], 0, 0, 0);
    }
  }

#pragma unroll
  for (int jn = 0; jn < 4; ++jn)
#pragma unroll
    for (int reg = 0; reg < 4; ++reg) {
      int qi = qrow + reg;
      if (qi < 1000)
        ctx[(long)(b * 1000 + qi) * 1024 + h * 64 + jn * 16 + ln] = f2bf(cacc[jn][reg]);
    }
}

// ---------------- launch ----------------------------------------------------
extern "C" void kernel_launch(void* const* d_in, const int* in_sizes, int n_in,
                              void* d_out, int out_size, void* d_ws, size_t ws_size,
                              hipStream_t stream)
{
  const float* q  = (const float*)d_in[0];
  const float* k  = (const float*)d_in[1];
  const float* v  = (const float*)d_in[2];
  const int*  msk = (const int*)d_in[3];
  const float* Wq = (const float*)d_in[4];
  const float* bq = (const float*)d_in[5];
  const float* Wk = (const float*)d_in[6];
  const float* bk = (const float*)d_in[7];
  const float* Wv = (const float*)d_in[8];
  const float* bv = (const float*)d_in[9];
  const float* Wp = (const float*)d_in[10];
  const float* bp = (const float*)d_in[11];

  u16* ws  = (u16*)d_ws;                     // 56 MB total
  u16* Qc  = ws;                             // [4000][1024] bf16 (q cast; ctx aliases later)
  u16* Kc  = ws + 4096000u;                  // [4000][1024] bf16 (k cast)
  u16* Vc  = ws + 2u * 4096000u;             // [4000][1024] bf16 (v cast)
  u16* Qb  = ws + 3u * 4096000u;             // [4000][1024] bf16 (Q proj)
  u16* Kb  = ws + 4u * 4096000u;             // [4000][1024] bf16 (K proj)
  u16* Vb  = ws + 5u * 4096000u;             // [4000][1024] bf16 (V proj)
  u16* wqb = ws + 6u * 4096000u;             // [1024][1024] bf16
  u16* wkb = wqb + (1u << 20);
  u16* wvb = wkb + (1u << 20);
  u16* wpb = wvb + (1u << 20);
  u16* ctx = Qc;                             // alias: Qc dead after QKV GEMM

  float* Xout = (float*)d_out;               // [4000][1024] f32 (output x)
  float* Aout = Xout + 4096000;              // [64][1000][1000] f32 (output A)

  convw_kernel<<<dim3(512, 1, 4), 256, 0, stream>>>(Wq, Wk, Wv, Wp, wqb, wkb, wvb, wpb);
  convact_kernel<<<dim3(2000, 1, 3), 256, 0, stream>>>(q, k, v, Qc, Kc, Vc);
  // fused QKV projections: 128x128 tiles, grid (32,8,3)=768 blocks (3/CU)
  gemm_swz<128, 0><<<dim3(32, 8, 3), 256, 0, stream>>>(
      Qc, Kc, Vc, wqb, wkb, wvb, bq, bk, bv, Qb, Kb, Vb, 4000);
  MaskedMultiheadAttention_51591147160164_kernel<<<dim3(16, 64), 256, 0, stream>>>(
      Qb, Kb, Vb, msk, Aout, ctx);
  // output projection: 64x128 tiles, grid (63,8)=504 blocks (2/CU)
  gemm_swz<64, 1><<<dim3(63, 8, 1), 256, 0, stream>>>(
      ctx, ctx, ctx, wpb, wpb, wpb, bp, bp, bp, Xout, Xout, Xout, 4000);
}